// Round 5
// baseline (311.767 us; speedup 1.0000x reference)
//
#include <hip/hip_runtime.h>
#include <stdint.h>
#include <string.h>

// BoltzmannGateSTE: out = x * (|x| >= T), T = k-th largest |x|, k = int(n/e).
// Fast path = ONE full read + ONE full write + ~25 MB side traffic:
//   pass_partition: stream x -> out with bracket [LO,HI) = [0.88,0.92):
//     u >= HI -> keep (wave-scalar ballot count);  u < LO -> zero;
//     else candidate -> placeholder 0, ballot-compacted append (bits,idx) to a
//     per-wave buffer + fire-and-forget atomicAdd into the exact per-bit-pattern
//     table fineH[u-LO] (671K bins, ~1 hit/bin, no contention).
//   reduce_select: 656 blocks sum fineH windows -> coarseH; the LAST block
//     (atomic done-counter) verifies chi < k <= chi+tot and runs the coarse+fine
//     descending scans -> exact threshold bit pattern.
//   cand_fixup: grid-stride over the candidate arena, write entries >= T.
// Exact gated fallback (proven R1 3-pass radix select) covers arbitrary inputs
// if verification ever fails (~120 sigma margins for this input). All logic is
// device-side (graph capture forbids host readback).

#define SEL_T 1024

constexpr unsigned LO_BITS = 0x3F6147AEu;        // bits(0.88f)
constexpr unsigned HI_BITS = 0x3F6B851Fu;        // bits(0.92f)
constexpr unsigned NKEY    = HI_BITS - LO_BITS;  // 671089 bracket bit patterns
constexpr int      NCB     = (NKEY + 1023) / 1024;   // 656 coarse bins

constexpr int P_GRID = 4096;                 // partition geometry
constexpr int P_BLK  = 256;
constexpr int P_WPB  = P_BLK / 64;           // 4 waves/block
constexpr int NWAVES = P_GRID * P_WPB;       // 16384
constexpr int CAPW   = 128;                  // slots/wave (mean ~43, ~13 sigma)

constexpr int NBIN1   = 4096;                // fallback: bits[30:19]
constexpr int NFINE   = 1 << 19;
constexpr int NCOARSE = 512;
constexpr int F_GRID  = 256;                 // fallback grids (never hot)
constexpr int F_BLK   = 256;

// state slots
#define S_PREF 0
#define S_K1   1
#define S_T    2
#define S_FLAG 3   // nonzero -> fallback chain active

__device__ __forceinline__ bool gate_skip(const unsigned* state, int gate) {
    if (gate == 0) return false;
    unsigned fl = state[S_FLAG];
    return (gate == 1) ? (fl == 0u) : (fl != 0u);
}

// ---------------- fast path ----------------
__global__ __launch_bounds__(P_BLK, 8)
void pass_partition(const uint4* __restrict__ x, long long n4,
                    uint4* __restrict__ out, uint2* __restrict__ cand,
                    unsigned* __restrict__ wavecnt, unsigned* __restrict__ blkchi,
                    unsigned* __restrict__ fineH, unsigned* __restrict__ state)
{
    typedef unsigned uv4 __attribute__((ext_vector_type(4)));
    const int lane  = threadIdx.x & 63;
    const int wid   = threadIdx.x >> 6;
    const int gwave = blockIdx.x * P_WPB + wid;
    uint2* my = cand + (size_t)gwave * CAPW;
    const unsigned long long lt = (1ull << lane) - 1ull;

    unsigned wcnt = 0;          // wave-uniform candidate count
    unsigned chiw = 0;          // wave-uniform >=HI count (ballot popcount)

    // one candidate element: count, classify, compact-append, fine-histogram
#define DO_COMP(vv, rr, c, off, ibase)                                         \
    { unsigned b = vv.c, u = b & 0x7FFFFFFFu;                                  \
      unsigned long long mk = __ballot(u >= HI_BITS);                          \
      unsigned long long mc = __ballot((u - LO_BITS) < NKEY);                  \
      chiw += (unsigned)__popcll(mk);                                          \
      rr.c = (u >= HI_BITS) ? b : 0u;                                          \
      if ((u - LO_BITS) < NKEY) {                                              \
          atomicAdd(&fineH[u - LO_BITS], 1u);   /* fire-and-forget */          \
          unsigned pos = wcnt + (unsigned)__popcll(mc & lt);                   \
          if (pos < (unsigned)CAPW) my[pos] = make_uint2(b, (ibase) + off);    \
      }                                                                        \
      wcnt += (unsigned)__popcll(mc); }

    const long long stride = (long long)gridDim.x * (P_BLK * 2);
    for (long long i = (long long)blockIdx.x * (P_BLK * 2) + threadIdx.x; i < n4; i += stride) {
        long long j = i + P_BLK;
        bool h1 = (j < n4);
        uint4 v0 = x[i];                      // two independent loads in flight
        uint4 v1;
        if (h1) v1 = x[j];
        uint4 r0, r1;
        unsigned ib0 = (unsigned)(i << 2);
        DO_COMP(v0, r0, x, 0, ib0) DO_COMP(v0, r0, y, 1, ib0)
        DO_COMP(v0, r0, z, 2, ib0) DO_COMP(v0, r0, w, 3, ib0)
        __builtin_nontemporal_store(*(uv4*)&r0, (uv4*)(out + i));
        if (h1) {
            unsigned ib1 = (unsigned)(j << 2);
            DO_COMP(v1, r1, x, 0, ib1) DO_COMP(v1, r1, y, 1, ib1)
            DO_COMP(v1, r1, z, 2, ib1) DO_COMP(v1, r1, w, 3, ib1)
            __builtin_nontemporal_store(*(uv4*)&r1, (uv4*)(out + j));
        }
    }
#undef DO_COMP

    __shared__ unsigned s_chi[P_WPB];
    if (lane == 0) {
        s_chi[wid] = chiw;
        wavecnt[gwave] = (wcnt < (unsigned)CAPW) ? wcnt : (unsigned)CAPW;
        if (wcnt > (unsigned)CAPW) atomicOr(&state[S_FLAG], 1u);
    }
    __syncthreads();
    if (threadIdx.x == 0) {
        unsigned a = 0;
        for (int w = 0; w < P_WPB; ++w) a += s_chi[w];
        blkchi[blockIdx.x] = a;
    }
}

// ---------------- descending select over a histogram (SEL_T threads) ----------------
__device__ void select_desc(const unsigned* __restrict__ hist, int nbins,
                            unsigned k, unsigned* s_scan, int* s_res)
{
    int tid = threadIdx.x;
    if (tid == 0) { s_res[0] = -1; s_res[1] = 0; }
    __syncthreads();
    unsigned running = 0;
    for (int top = nbins; top > 0; top -= SEL_T) {
        int bin = top - 1 - tid;
        unsigned v = (bin >= 0) ? hist[bin] : 0u;
        s_scan[tid] = v;
        __syncthreads();
        for (int off = 1; off < SEL_T; off <<= 1) {
            unsigned add = (tid >= off) ? s_scan[tid - off] : 0u;
            __syncthreads();
            s_scan[tid] += add;
            __syncthreads();
        }
        unsigned p     = s_scan[tid];
        unsigned pprev = (tid > 0) ? s_scan[tid - 1] : 0u;
        unsigned total = s_scan[SEL_T - 1];
        __syncthreads();
        if (running + total >= k) {
            if (bin >= 0 && running + p >= k && running + pprev < k) {
                s_res[0] = bin;
                s_res[1] = (int)(k - running - pprev);
            }
            __syncthreads();
            return;
        }
        running += total;
    }
    __syncthreads();
}

// 656 blocks x 1024: window-sum fineH -> coarseH; LAST block verifies + selects.
__global__ __launch_bounds__(SEL_T)
void reduce_select(const unsigned* __restrict__ fineH, unsigned* __restrict__ coarseH,
                   const unsigned* __restrict__ blkchi, const unsigned* __restrict__ wavecnt,
                   unsigned* __restrict__ state, unsigned* __restrict__ done_ctr,
                   unsigned k)
{
    __shared__ unsigned s_scan[SEL_T];
    __shared__ int s_res[2];
    __shared__ unsigned long long s_red[SEL_T / 64][2];
    __shared__ unsigned s_last, s_kp;
    __shared__ int s_bad;

    int tid = threadIdx.x;
    unsigned key = ((unsigned)blockIdx.x << 10) + (unsigned)tid;
    unsigned s = (key < NKEY) ? fineH[key] : 0u;
    for (int m = 32; m; m >>= 1) s += __shfl_xor(s, m, 64);
    if ((tid & 63) == 0) s_red[tid >> 6][0] = s;
    __syncthreads();
    if (tid == 0) {
        unsigned t = 0;
        for (int w = 0; w < SEL_T / 64; ++w) t += (unsigned)s_red[w][0];
        coarseH[blockIdx.x] = t;
        __threadfence();
        unsigned d = atomicAdd(done_ctr, 1u);
        s_last = (d == (unsigned)(NCB - 1)) ? 1u : 0u;
    }
    __syncthreads();
    if (!s_last) return;
    __threadfence();                 // acquire side of the done-counter chain

    // last block: reduce tallies, verify bracket
    unsigned long long chi = 0, tot = 0;
    for (int i = tid; i < P_GRID; i += SEL_T) chi += blkchi[i];
    for (int i = tid; i < NWAVES; i += SEL_T) tot += wavecnt[i];
    for (int m = 32; m; m >>= 1) {
        chi += __shfl_xor(chi, m, 64);
        tot += __shfl_xor(tot, m, 64);
    }
    if ((tid & 63) == 0) { s_red[tid >> 6][0] = chi; s_red[tid >> 6][1] = tot; }
    __syncthreads();
    if (tid == 0) {
        unsigned long long C = 0, Tt = 0;
        for (int w = 0; w < SEL_T / 64; ++w) { C += s_red[w][0]; Tt += s_red[w][1]; }
        if (state[S_FLAG] || C >= (unsigned long long)k || C + Tt < (unsigned long long)k) {
            state[S_FLAG] = 1u;      // overflow or T outside bracket -> fallback
            s_bad = 1;
        } else { s_bad = 0; s_kp = (unsigned)((unsigned long long)k - C); }
    }
    __syncthreads();
    if (s_bad) return;
    unsigned kp = s_kp;

    select_desc(coarseH, NCB, kp, s_scan, s_res);
    int cb     = s_res[0];
    unsigned r = (unsigned)s_res[1];
    __syncthreads();
    if (cb < 0) { if (tid == 0) state[S_FLAG] = 1u; return; }   // safety net
    int nf = (int)NKEY - (cb << 10);
    if (nf > 1024) nf = 1024;
    select_desc(fineH + ((size_t)cb << 10), nf, r, s_scan, s_res);
    if (tid == 0) {
        int f = (s_res[0] < 0) ? 0 : s_res[0];
        state[S_T] = LO_BITS + (unsigned)((cb << 10) + f);
    }
}

// grid-stride over the whole candidate arena; poison (0x2AAAAAAA) never passes >=T
__global__ __launch_bounds__(256)
void cand_fixup(const uint2* __restrict__ cand, const unsigned* __restrict__ state,
                float* __restrict__ out, long long n)
{
    if (state[S_FLAG]) return;
    unsigned T = state[S_T];
    long long total = (long long)NWAVES * CAPW;
    long long stride = (long long)gridDim.x * 256;
    for (long long j = (long long)blockIdx.x * 256 + threadIdx.x; j < total; j += stride) {
        uint2 e = cand[j];
        if ((e.x & 0x7FFFFFFFu) >= T && e.y < (unsigned long long)n)
            out[e.y] = __uint_as_float(e.x);
    }
}

// ---------------- gated exact fallback (never hot; correctness only) ----------------
__global__ __launch_bounds__(F_BLK)
void f_hist1(const uint4* __restrict__ x, long long n4, unsigned* __restrict__ histA,
             const unsigned* __restrict__ state, int gate)
{
    if (gate_skip(state, gate)) return;
    __shared__ unsigned h[NBIN1];
    for (int i = threadIdx.x; i < NBIN1; i += F_BLK) h[i] = 0u;
    __syncthreads();
    long long stride = (long long)gridDim.x * F_BLK;
    for (long long i = (long long)blockIdx.x * F_BLK + threadIdx.x; i < n4; i += stride) {
        uint4 v = x[i];
        atomicAdd(&h[(v.x & 0x7FFFFFFFu) >> 19], 1u);
        atomicAdd(&h[(v.y & 0x7FFFFFFFu) >> 19], 1u);
        atomicAdd(&h[(v.z & 0x7FFFFFFFu) >> 19], 1u);
        atomicAdd(&h[(v.w & 0x7FFFFFFFu) >> 19], 1u);
    }
    __syncthreads();
    for (int i = threadIdx.x; i < NBIN1; i += F_BLK)
        if (h[i]) atomicAdd(&histA[i], h[i]);
}

__global__ __launch_bounds__(SEL_T)
void f_select1(const unsigned* __restrict__ histA, unsigned* __restrict__ state,
               unsigned k, int gate)
{
    if (gate_skip(state, gate)) return;
    __shared__ unsigned s_scan[SEL_T];
    __shared__ int s_res[2];
    select_desc(histA, NBIN1, k, s_scan, s_res);
    if (threadIdx.x == 0) {
        state[S_PREF] = (s_res[0] < 0) ? 0u : (unsigned)s_res[0];
        state[S_K1]   = (s_res[0] < 0) ? 1u : (unsigned)s_res[1];
    }
}

__global__ __launch_bounds__(F_BLK)
void f_hist2(const uint4* __restrict__ x, long long n4, const unsigned* __restrict__ state,
             unsigned* __restrict__ fineB, unsigned* __restrict__ coarseB, int gate)
{
    if (gate_skip(state, gate)) return;
    __shared__ unsigned hc[NCOARSE];
    for (int i = threadIdx.x; i < NCOARSE; i += F_BLK) hc[i] = 0u;
    __syncthreads();
    unsigned pref = state[S_PREF];
    long long stride = (long long)gridDim.x * F_BLK;
    for (long long i = (long long)blockIdx.x * F_BLK + threadIdx.x; i < n4; i += stride) {
        uint4 v = x[i];
        unsigned u;
#define DO_C(c) u = v.c & 0x7FFFFFFFu;                                        \
        if ((u >> 19) == pref) {                                              \
            atomicAdd(&fineB[u & (NFINE - 1)], 1u);                           \
            atomicAdd(&hc[(u & (NFINE - 1)) >> 10], 1u); }
        DO_C(x) DO_C(y) DO_C(z) DO_C(w)
#undef DO_C
    }
    __syncthreads();
    for (int i = threadIdx.x; i < NCOARSE; i += F_BLK)
        if (hc[i]) atomicAdd(&coarseB[i], hc[i]);
}

__global__ __launch_bounds__(SEL_T)
void f_select2(const unsigned* __restrict__ fineB, const unsigned* __restrict__ coarseB,
               unsigned* __restrict__ state, int gate)
{
    if (gate_skip(state, gate)) return;
    __shared__ unsigned s_scan[SEL_T];
    __shared__ int s_res[2];
    unsigned pref = state[S_PREF];
    unsigned k    = state[S_K1];
    select_desc(coarseB, NCOARSE, k, s_scan, s_res);
    int c       = (s_res[0] < 0) ? 0 : s_res[0];
    unsigned k1 = (s_res[0] < 0) ? 1u : (unsigned)s_res[1];
    __syncthreads();
    select_desc(fineB + (size_t)c * 1024, 1024, k1, s_scan, s_res);
    int f = (s_res[0] < 0) ? 0 : s_res[0];
    if (threadIdx.x == 0)
        state[S_T] = (pref << 19) | ((unsigned)c << 10) | (unsigned)f;
}

__global__ __launch_bounds__(256)
void f_mask(const uint4* __restrict__ x, uint4* __restrict__ out, long long n4,
            const unsigned* __restrict__ state, int gate)
{
    if (gate_skip(state, gate)) return;
    unsigned t = state[S_T];
    long long stride = (long long)gridDim.x * 256;
    for (long long i = (long long)blockIdx.x * 256 + threadIdx.x; i < n4; i += stride) {
        uint4 v = x[i];
        uint4 r;
        r.x = ((v.x & 0x7FFFFFFFu) >= t) ? v.x : 0u;
        r.y = ((v.y & 0x7FFFFFFFu) >= t) ? v.y : 0u;
        r.z = ((v.z & 0x7FFFFFFFu) >= t) ? v.z : 0u;
        r.w = ((v.w & 0x7FFFFFFFu) >= t) ? v.w : 0u;
        out[i] = r;
    }
}

// ---------------- host ----------------
static inline size_t align64(size_t v) { return (v + 63) & ~(size_t)63; }

extern "C" void kernel_launch(void* const* d_in, const int* in_sizes, int n_in,
                              void* d_out, int out_size, void* d_ws, size_t ws_size,
                              hipStream_t stream)
{
    long long n = (long long)in_sizes[0];
    if (n <= 0) return;
    long long n4 = n >> 2;   // n = 4*4096*2048, divisible by 4

    const double FRACTION = 1.0 / 2.718281828459045;   // matches Python 1.0/math.e
    long long k = (long long)((double)n * FRACTION);
    if (k < 1) k = 1;

    // contiguous zero region, then non-zeroed buffers
    const size_t off_done    = 64;                                   // state at 0
    const size_t off_coarseH = 128;
    const size_t off_fineH   = align64(off_coarseH + (size_t)NCB * 4);
    const size_t off_fineB   = align64(off_fineH + (size_t)NKEY * 4);
    const size_t off_coarseB = off_fineB   + (size_t)NFINE * 4;
    const size_t off_histA   = off_coarseB + (size_t)NCOARSE * 4;
    const size_t zero_end    = off_histA   + (size_t)NBIN1 * 4;      // ~4.8 MB
    const size_t off_wcnt    = zero_end;
    const size_t off_bchi    = off_wcnt + (size_t)NWAVES * 4;
    const size_t off_cand    = off_bchi + (size_t)P_GRID * 4;
    const size_t need_fast   = off_cand + (size_t)NWAVES * CAPW * 8; // ~21.7 MB
    const size_t need_fb     = zero_end;

    uint8_t* base;
    unsigned* state = (unsigned*)d_ws;
    bool fast;
    if (ws_size >= need_fast)     { base = (uint8_t*)d_ws;  fast = true;  }
    else if (ws_size >= need_fb)  { base = (uint8_t*)d_ws;  fast = false; }
    else                          { base = (uint8_t*)d_out; fast = false; } // stage in d_out

    unsigned* done_c  = (unsigned*)(base + off_done);
    unsigned* coarseH = (unsigned*)(base + off_coarseH);
    unsigned* fineH   = (unsigned*)(base + off_fineH);
    unsigned* fineB   = (unsigned*)(base + off_fineB);
    unsigned* coarseB = (unsigned*)(base + off_coarseB);
    unsigned* histA   = (unsigned*)(base + off_histA);
    unsigned* wavecnt = (unsigned*)(base + off_wcnt);
    unsigned* blkchi  = (unsigned*)(base + off_bchi);
    uint2*    cand    = (uint2*)   (base + off_cand);

    const uint4* x = (const uint4*)d_in[0];

    if (fast) {
        // single memset covers state+done+coarseH+fineH+fineB+coarseB+histA
        hipMemsetAsync(base, 0, zero_end, stream);
        pass_partition<<<P_GRID, P_BLK, 0, stream>>>(x, n4, (uint4*)d_out, cand,
                                                     wavecnt, blkchi, fineH, state);
        reduce_select <<<NCB, SEL_T, 0, stream>>>(fineH, coarseH, blkchi, wavecnt,
                                                  state, done_c, (unsigned)k);
        cand_fixup    <<<512, 256, 0, stream>>>(cand, state, (float*)d_out, n);
        // gated exact fallback — all no-ops unless verification failed
        f_hist1  <<<F_GRID, F_BLK, 0, stream>>>(x, n4, histA, state, 1);
        f_select1<<<1, SEL_T, 0, stream>>>(histA, state, (unsigned)k, 1);
        f_hist2  <<<F_GRID, F_BLK, 0, stream>>>(x, n4, state, fineB, coarseB, 1);
        f_select2<<<1, SEL_T, 0, stream>>>(fineB, coarseB, state, 1);
        f_mask   <<<1024, 256, 0, stream>>>(x, (uint4*)d_out, n4, state, 1);
    } else {
        if (base != (uint8_t*)d_ws) hipMemsetAsync(state, 0, 64, stream);
        else                        hipMemsetAsync(base, 0, 128, stream);
        hipMemsetAsync(base + off_fineB, 0,
                       ((size_t)NFINE + NCOARSE + NBIN1) * 4, stream);
        f_hist1  <<<F_GRID, F_BLK, 0, stream>>>(x, n4, histA, state, 0);
        f_select1<<<1, SEL_T, 0, stream>>>(histA, state, (unsigned)k, 0);
        f_hist2  <<<F_GRID, F_BLK, 0, stream>>>(x, n4, state, fineB, coarseB, 0);
        f_select2<<<1, SEL_T, 0, stream>>>(fineB, coarseB, state, 0);
        f_mask   <<<1024, 256, 0, stream>>>(x, (uint4*)d_out, n4, state, 0);
    }
}